// Round 8
// baseline (659.694 us; speedup 1.0000x reference)
//
#include <hip/hip_runtime.h>
#include <hip/hip_fp16.h>
#include <math.h>

#define GRID_R 128
#define DATA_DIM 28
#define PAD_DIM 32
#define NSEG 8
#define SEG_STEPS 32
#define STEP_SIZE 0.001f
#define BG 1.0f

// packed half2 for v_dot2
typedef _Float16 h2f __attribute__((ext_vector_type(2)));

#if __has_builtin(__builtin_amdgcn_fdot2)
__device__ __forceinline__ float fdot2(h2f a, h2f b, float c) {
    return __builtin_amdgcn_fdot2(a, b, c, false);
}
#else
__device__ __forceinline__ float fdot2(h2f a, h2f b, float c) {
    return fmaf((float)a.x, (float)b.x, fmaf((float)a.y, (float)b.y, c));
}
#endif

#if __has_builtin(__builtin_amdgcn_exp2f)
__device__ __forceinline__ float fexp2(float x)    { return __builtin_amdgcn_exp2f(x); }
__device__ __forceinline__ float fexp2neg(float x) { return __builtin_amdgcn_exp2f(-x); }
#else
__device__ __forceinline__ float fexp2(float x) {
    float r; asm("v_exp_f32 %0, %1" : "=v"(r) : "v"(x)); return r;
}
__device__ __forceinline__ float fexp2neg(float x) {
    float r; asm("v_exp_f32 %0, -%1" : "=v"(r) : "v"(x)); return r;
}
#endif

#if __has_builtin(__builtin_amdgcn_rcpf)
__device__ __forceinline__ float frcp(float x) { return __builtin_amdgcn_rcpf(x); }
#else
__device__ __forceinline__ float frcp(float x) {
    float r; asm("v_rcp_f32 %0, %1" : "=v"(r) : "v"(x)); return r;
}
#endif

// ---------------------------------------------------------------------------
// Shared per-step geometry — bit-identical to the verified kernel (voxel
// picks at cell boundaries are rounding-sensitive). Safe for ANY finite t
// (clamped index, finite dt).
// ---------------------------------------------------------------------------
__device__ __forceinline__ float march_step(
    float t, float ox, float oy, float oz,
    float dx, float dy, float dz,
    float idx, float idy, float idz, int* flat)
{
    float px = (ox + t*dx) * 128.0f;
    float py = (oy + t*dy) * 128.0f;
    float pz = (oz + t*dz) * 128.0f;
    float fx = fminf(fmaxf(floorf(px), 0.0f), 127.0f);
    float fy = fminf(fmaxf(floorf(py), 0.0f), 127.0f);
    float fz = fminf(fmaxf(floorf(pz), 0.0f), 127.0f);
    float ff = fmaf(fx, 16384.0f, fmaf(fy, 128.0f, fz));   // exact, < 2^21
    *flat = (int)ff;
    float cx = px - fx, cy = py - fy, cz = pz - fz;
    float a1x = -cx*idx, a1y = -cy*idy, a1z = -cz*idz;
    float a2x = a1x+idx, a2y = a1y+idy, a2z = a1z+idz;
    float e1 = fminf(fminf(fmaxf(a1x,a2x), fmaxf(a1y,a2y)), fmaxf(a1z,a2z));
    e1 = fminf(e1, 1e9f);
    return e1 * (1.0f/128.0f) + STEP_SIZE;
}

#define RAY_SETUP(i)                                                          \
    float ox = origins[3*(i)+0], oy = origins[3*(i)+1], oz = origins[3*(i)+2];\
    float dx = dirs_in[3*(i)+0], dy = dirs_in[3*(i)+1], dz = dirs_in[3*(i)+2];\
    float dn = sqrtf(dx*dx + dy*dy + dz*dz);                                  \
    float rdn = 1.0f / dn;                                                    \
    dx *= rdn; dy *= rdn; dz *= rdn;                                          \
    float idx = 1.0f / (dx + 1e-9f);                                          \
    float idy = 1.0f / (dy + 1e-9f);                                          \
    float idz = 1.0f / (dz + 1e-9f);                                          \
    float t1x = -ox*idx, t1y = -oy*idy, t1z = -oz*idz;                        \
    float t2x = t1x+idx, t2y = t1y+idy, t2z = t1z+idz;                        \
    float t0   = fmaxf(fmaxf(fmaxf(fminf(t1x,t2x), fminf(t1y,t2y)), fminf(t1z,t2z)), 0.0f); \
    float tmax = fminf(fminf(fminf(fmaxf(t1x,t2x), fmaxf(t1y,t2y)), fmaxf(t1z,t2z)), 1e9f);

// ---------------------------------------------------------------------------
// Fused pre-pass, two block ranges (mask pass eliminated — the dense fp16
// sigma array is written by the convert threads for free):
//   [0, nGeomB)             : per-ray geometry checkpoints
//   [nGeomB, nGeomB+nConvB) : fp32 -> fp16 convert (2 thr/voxel) + dense
//                             fp16 sigma array Sg[v] (4 MB, L2/L3-resident)
//
// CHANNEL-MAJOR voxel record (32 halfs = 64 B), s[] = half index:
//   s[ 0.. 8] = f0..f8  (ch0), s[9]  = pad
//   s[10..18] = f9..f17 (ch1), s[19] = pad
//   s[20..28] = f18..f26(ch2), s[29] = pad
//   s[30]     = sigma (f27),   s[31] = pad
// ---------------------------------------------------------------------------
__global__ __launch_bounds__(256) void prep_kernel(
    const float* __restrict__ tree, __half* __restrict__ vox, int nvox,
    const float* __restrict__ origins, const float* __restrict__ dirs_in,
    float* __restrict__ ckpt, __half* __restrict__ sg_out,
    int nB, int nGeomB)
{
    int bid = (int)blockIdx.x;
    if (bid < nGeomB) {
        // ---- geometry checkpoints (one thread per ray, no gathers) ----
        int i = bid * 256 + threadIdx.x;
        if (i >= nB) return;
        RAY_SETUP(i);
        float ck[NSEG];
        float t = t0;
        ck[0] = t0;
#pragma unroll
        for (int k = 1; k < NSEG; ++k) {
            if (t < tmax) {
                for (int j = 0; j < SEG_STEPS; ++j) {
                    int fl;
                    t += march_step(t, ox, oy, oz, dx, dy, dz, idx, idy, idz, &fl);
                    if (t >= tmax) break;
                }
            }
            ck[k] = t;
        }
        float* cp = ckpt + (size_t)i * NSEG;
        *(float4*)(cp + 0) = make_float4(ck[0], ck[1], ck[2], ck[3]);
        *(float4*)(cp + 4) = make_float4(ck[4], ck[5], ck[6], ck[7]);
    } else {
        // ---- fp32 -> fp16 convert + channel-major reorder, 2 thr/voxel ----
        int tid2 = (bid - nGeomB) * 256 + threadIdx.x;
        int v = tid2 >> 1;
        int q = tid2 & 1;
        if (v >= nvox) return;
        const float* src = tree + (size_t)v * DATA_DIM;
        uint4* d = (uint4*)(vox + (size_t)v * PAD_DIM) + q * 2;
        union Q { __half2 h[4]; uint4 u; } w;
        if (q == 0) {
            float4 L0 = *(const float4*)(src + 0);   // f0..f3
            float4 L1 = *(const float4*)(src + 4);   // f4..f7
            float4 L2 = *(const float4*)(src + 8);   // f8..f11
            float4 L3 = *(const float4*)(src + 12);  // f12..f15
            w.h[0] = __floats2half2_rn(L0.x, L0.y);  // f0 f1
            w.h[1] = __floats2half2_rn(L0.z, L0.w);  // f2 f3
            w.h[2] = __floats2half2_rn(L1.x, L1.y);  // f4 f5
            w.h[3] = __floats2half2_rn(L1.z, L1.w);  // f6 f7
            d[0] = w.u;
            w.h[0] = __floats2half2_rn(L2.x, 0.f);   // f8 pad
            w.h[1] = __floats2half2_rn(L2.y, L2.z);  // f9 f10
            w.h[2] = __floats2half2_rn(L2.w, L3.x);  // f11 f12
            w.h[3] = __floats2half2_rn(L3.y, L3.z);  // f13 f14
            d[1] = w.u;
        } else {
            float4 M0 = *(const float4*)(src + 12);  // f12..f15
            float4 M1 = *(const float4*)(src + 16);  // f16..f19
            float4 M2 = *(const float4*)(src + 20);  // f20..f23
            float4 M3 = *(const float4*)(src + 24);  // f24..f27
            w.h[0] = __floats2half2_rn(M0.w, M1.x);  // f15 f16
            w.h[1] = __floats2half2_rn(M1.y, 0.f);   // f17 pad
            w.h[2] = __floats2half2_rn(M1.z, M1.w);  // f18 f19
            w.h[3] = __floats2half2_rn(M2.x, M2.y);  // f20 f21
            d[0] = w.u;
            w.h[0] = __floats2half2_rn(M2.z, M2.w);  // f22 f23
            w.h[1] = __floats2half2_rn(M3.x, M3.y);  // f24 f25
            w.h[2] = __floats2half2_rn(M3.z, 0.f);   // f26 pad
            w.h[3] = __floats2half2_rn(M3.w, 0.f);   // sigma pad
            d[1] = w.u;
            sg_out[v] = __low2half(w.h[3]);          // dense sigma (same rounding)
        }
    }
}

// ---------------------------------------------------------------------------
// Main march: r5's verified structure + one-step-ahead SIGMA rotation in
// plain C (no inline-asm loads, no counted vmcnt — r7 proved hand-counted
// waits are unsafe amid compiler-generated VMEM). Per iteration:
//   1. next-step geometry (pure VALU) + issue sg[f_next] load — no data dep
//      on this step, so the compiler schedules the load a full iteration
//      before its consumer and inserts its own correctly-counted wait;
//   2. current step: occ = (sgA > 0) known WITHOUT touching the 64 B record
//      (light chain decoupled from the record gather);
//   3. record fetch + shade only when occ (same divergent-branch structure
//      that r5 verified).
// occ = fp16 sg > 0 is output-identical to r5's f32 mask: the only
// divergent case (tiny positive f32 rounding to fp16 +0) contributes
// w = 0 / att = 1 either way. t-sequence and shading arithmetic are
// bit-identical to r5.
// ---------------------------------------------------------------------------
typedef union { uint4 u[4]; h2f h[16]; _Float16 s[32]; } Rec;

__global__ __launch_bounds__(256, 8) void march_kernel(
    const __half* __restrict__ vox_grid,
    const __half* __restrict__ sig_arr,
    const float* __restrict__ origins,
    const float* __restrict__ dirs_in,
    const float* __restrict__ viewdirs,
    const float* __restrict__ invradius,
    const float* __restrict__ ckpt,
    float* __restrict__ out, int nB)
{
    int tid = blockIdx.x * blockDim.x + threadIdx.x;
    int ray = tid >> 3;
    int seg = tid & 7;
    if (ray >= nB) return;

    RAY_SETUP(ray);

    float vx = viewdirs[3*ray+0], vy = viewdirs[3*ray+1], vz = viewdirs[3*ray+2];
    float irx = invradius[0], iry = invradius[1], irz = invradius[2];
    float qx = dx / irx, qy = dy / iry, qz = dz / irz;
    float delta_scale = sqrtf(qx*qx + qy*qy + qz*qz);

    const float C1 = 0.4886025119029199f;
    const float L2E = 1.4426950408889634f;   // log2(e), folded into SH + att
    float sh0 = 0.28209479177387814f;
    float sh1 = -C1 * vy;
    float sh2 =  C1 * vz;
    float sh3 = -C1 * vx;
    float sh4 =  1.0925484305920792f  * vx * vy;
    float sh5 = -1.0925484305920792f * vy * vz;
    float sh6 =  0.31539156525252005f * (2.0f*vz*vz - vx*vx - vy*vy);
    float sh7 = -1.0925484305920792f * vx * vz;
    float sh8 =  0.5462742152960396f  * (vx*vx - vy*vy);

    // loop-invariant fp16 coefficient pairs (pre-scaled by log2 e)
    h2f S01 = { (_Float16)(sh0*L2E), (_Float16)(sh1*L2E) };
    h2f S23 = { (_Float16)(sh2*L2E), (_Float16)(sh3*L2E) };
    h2f S45 = { (_Float16)(sh4*L2E), (_Float16)(sh5*L2E) };
    h2f S67 = { (_Float16)(sh6*L2E), (_Float16)(sh7*L2E) };
    h2f S8z = { (_Float16)(sh8*L2E), (_Float16)0.0f      };
    float nds = -delta_scale * L2E;          // att = 2^(dt*sigma*nds)

    float t = ckpt[(size_t)ray * NSEG + seg];
    float light = 1.0f;                      // segment-local transmittance
    float o0 = 0.f, o1 = 0.f, o2 = 0.f;

    // prologue: geometry + sigma for step 0 (safe for any finite t)
    int fA;
    float dtA = march_step(t, ox, oy, oz, dx, dy, dz, idx, idy, idz, &fA);
    float sgA = __half2float(sig_arr[fA]);

    for (int j = 0; j < SEG_STEPS; ++j) {
        if (t >= tmax) break;

        // ---- step j+1 geometry + sigma issue (independent of step j) ----
        float tn = t + dtA;
        int fB;
        float dtB = march_step(tn, ox, oy, oz, dx, dy, dz, idx, idy, idz, &fB);
        float sgB = __half2float(sig_arr[fB]);

        // ---- step j: light chain + record shade, gated on sigma only ----
        if (sgA > 0.0f) {
            const uint4* vp = (const uint4*)(vox_grid + (size_t)fA * PAD_DIM);
            Rec rec;
            rec.u[0] = vp[0]; rec.u[1] = vp[1];
            rec.u[2] = vp[2]; rec.u[3] = vp[3];

            float att = fexp2(dtA * sgA * nds);
            float la  = light * att;                 // light AFTER this step
            float w   = light - la;                  // = light*(1-att)
            light = la;

            // r_c pre-scaled by log2(e): sigmoid = rcp(1 + 2^-r)
            float r0 = fdot2(rec.h[ 4], S8z, fdot2(rec.h[ 3], S67,
                       fdot2(rec.h[ 2], S45, fdot2(rec.h[ 1], S23,
                       fdot2(rec.h[ 0], S01, 0.0f)))));
            float r1 = fdot2(rec.h[ 9], S8z, fdot2(rec.h[ 8], S67,
                       fdot2(rec.h[ 7], S45, fdot2(rec.h[ 6], S23,
                       fdot2(rec.h[ 5], S01, 0.0f)))));
            float r2 = fdot2(rec.h[14], S8z, fdot2(rec.h[13], S67,
                       fdot2(rec.h[12], S45, fdot2(rec.h[11], S23,
                       fdot2(rec.h[10], S01, 0.0f)))));

            float g0 = frcp(1.0f + fexp2neg(r0));
            float g1 = frcp(1.0f + fexp2neg(r1));
            float g2 = frcp(1.0f + fexp2neg(r2));

            o0 = fmaf(w, g0, o0);
            o1 = fmaf(w, g1, o1);
            o2 = fmaf(w, g2, o2);
        }

        // rotate
        t = tn; fA = fB; dtA = dtB; sgA = sgB;
    }

    // ---- 8-lane combine (lanes 8m..8m+7 hold segments 0..7 of one ray) ----
    float l0 = __shfl(light, 0, 8);
    float l1 = __shfl(light, 1, 8);
    float l2 = __shfl(light, 2, 8);
    float l3 = __shfl(light, 3, 8);
    float l4 = __shfl(light, 4, 8);
    float l5 = __shfl(light, 5, 8);
    float l6 = __shfl(light, 6, 8);
    float l7 = __shfl(light, 7, 8);

    float P = 1.0f;
    if (seg > 0) P *= l0;
    if (seg > 1) P *= l1;
    if (seg > 2) P *= l2;
    if (seg > 3) P *= l3;
    if (seg > 4) P *= l4;
    if (seg > 5) P *= l5;
    if (seg > 6) P *= l6;
    float total_light = l0*l1*l2*l3*l4*l5*l6*l7;

    o0 *= P; o1 *= P; o2 *= P;
    o0 += __shfl_xor(o0, 1, 8); o0 += __shfl_xor(o0, 2, 8); o0 += __shfl_xor(o0, 4, 8);
    o1 += __shfl_xor(o1, 1, 8); o1 += __shfl_xor(o1, 2, 8); o1 += __shfl_xor(o1, 4, 8);
    o2 += __shfl_xor(o2, 1, 8); o2 += __shfl_xor(o2, 2, 8); o2 += __shfl_xor(o2, 4, 8);

    if (seg == 0) {
        out[3*ray+0] = o0 + total_light * BG;
        out[3*ray+1] = o1 + total_light * BG;
        out[3*ray+2] = o2 + total_light * BG;
    }
}

extern "C" void kernel_launch(void* const* d_in, const int* in_sizes, int n_in,
                              void* d_out, int out_size, void* d_ws, size_t ws_size,
                              hipStream_t stream) {
    const float* tree      = (const float*)d_in[0];
    const float* origins   = (const float*)d_in[1];
    const float* dirs      = (const float*)d_in[2];
    const float* viewdirs  = (const float*)d_in[3];
    const float* invradius = (const float*)d_in[4];
    float* out = (float*)d_out;

    int nB   = in_sizes[1] / 3;
    int nvox = in_sizes[0] / DATA_DIM;

    const int block = 256;
    __half* hgrid = (__half*)d_ws;
    float* ckpt = (float*)((char*)d_ws + (size_t)nvox * PAD_DIM * sizeof(__half));
    __half* sgarr = (__half*)((char*)ckpt + (size_t)nB * NSEG * sizeof(float));

    int nGeomB = (nB + block - 1) / block;
    int nConvB = (nvox * 2 + block - 1) / block;
    prep_kernel<<<nGeomB + nConvB, block, 0, stream>>>(
        tree, hgrid, nvox, origins, dirs, ckpt, sgarr, nB, nGeomB);

    int nmarch = nB * NSEG;
    march_kernel<<<(nmarch + block - 1) / block, block, 0, stream>>>(
        hgrid, sgarr, origins, dirs, viewdirs, invradius, ckpt, out, nB);
    (void)ws_size;
}

// Round 9
// 599.767 us; speedup vs baseline: 1.0999x; 1.0999x over previous
//
#include <hip/hip_runtime.h>
#include <hip/hip_fp16.h>
#include <math.h>

#define GRID_R 128
#define DATA_DIM 28
#define PAD_DIM 32
#define NSEG 8
#define SEG_STEPS 32
#define STEP_SIZE 0.001f
#define BG 1.0f

// packed half2 for v_dot2
typedef _Float16 h2f __attribute__((ext_vector_type(2)));

#if __has_builtin(__builtin_amdgcn_fdot2)
__device__ __forceinline__ float fdot2(h2f a, h2f b, float c) {
    return __builtin_amdgcn_fdot2(a, b, c, false);
}
#else
__device__ __forceinline__ float fdot2(h2f a, h2f b, float c) {
    return fmaf((float)a.x, (float)b.x, fmaf((float)a.y, (float)b.y, c));
}
#endif

#if __has_builtin(__builtin_amdgcn_exp2f)
__device__ __forceinline__ float fexp2(float x)    { return __builtin_amdgcn_exp2f(x); }
__device__ __forceinline__ float fexp2neg(float x) { return __builtin_amdgcn_exp2f(-x); }
#else
__device__ __forceinline__ float fexp2(float x) {
    float r; asm("v_exp_f32 %0, %1" : "=v"(r) : "v"(x)); return r;
}
__device__ __forceinline__ float fexp2neg(float x) {
    float r; asm("v_exp_f32 %0, -%1" : "=v"(r) : "v"(x)); return r;
}
#endif

#if __has_builtin(__builtin_amdgcn_rcpf)
__device__ __forceinline__ float frcp(float x) { return __builtin_amdgcn_rcpf(x); }
#else
__device__ __forceinline__ float frcp(float x) {
    float r; asm("v_rcp_f32 %0, %1" : "=v"(r) : "v"(x)); return r;
}
#endif

// ---------------------------------------------------------------------------
// Shared per-step geometry — bit-identical to the verified kernel (voxel
// picks at cell boundaries are rounding-sensitive). Safe for ANY finite t
// (clamped index, finite dt) — legal for speculative evaluation.
// ---------------------------------------------------------------------------
__device__ __forceinline__ float march_step(
    float t, float ox, float oy, float oz,
    float dx, float dy, float dz,
    float idx, float idy, float idz, int* flat)
{
    float px = (ox + t*dx) * 128.0f;
    float py = (oy + t*dy) * 128.0f;
    float pz = (oz + t*dz) * 128.0f;
    float fx = fminf(fmaxf(floorf(px), 0.0f), 127.0f);
    float fy = fminf(fmaxf(floorf(py), 0.0f), 127.0f);
    float fz = fminf(fmaxf(floorf(pz), 0.0f), 127.0f);
    float ff = fmaf(fx, 16384.0f, fmaf(fy, 128.0f, fz));   // exact, < 2^21
    *flat = (int)ff;
    float cx = px - fx, cy = py - fy, cz = pz - fz;
    float a1x = -cx*idx, a1y = -cy*idy, a1z = -cz*idz;
    float a2x = a1x+idx, a2y = a1y+idy, a2z = a1z+idz;
    float e1 = fminf(fminf(fmaxf(a1x,a2x), fmaxf(a1y,a2y)), fmaxf(a1z,a2z));
    e1 = fminf(e1, 1e9f);
    return e1 * (1.0f/128.0f) + STEP_SIZE;
}

#define RAY_SETUP(i)                                                          \
    float ox = origins[3*(i)+0], oy = origins[3*(i)+1], oz = origins[3*(i)+2];\
    float dx = dirs_in[3*(i)+0], dy = dirs_in[3*(i)+1], dz = dirs_in[3*(i)+2];\
    float dn = sqrtf(dx*dx + dy*dy + dz*dz);                                  \
    float rdn = 1.0f / dn;                                                    \
    dx *= rdn; dy *= rdn; dz *= rdn;                                          \
    float idx = 1.0f / (dx + 1e-9f);                                          \
    float idy = 1.0f / (dy + 1e-9f);                                          \
    float idz = 1.0f / (dz + 1e-9f);                                          \
    float t1x = -ox*idx, t1y = -oy*idy, t1z = -oz*idz;                        \
    float t2x = t1x+idx, t2y = t1y+idy, t2z = t1z+idz;                        \
    float t0   = fmaxf(fmaxf(fmaxf(fminf(t1x,t2x), fminf(t1y,t2y)), fminf(t1z,t2z)), 0.0f); \
    float tmax = fminf(fminf(fminf(fmaxf(t1x,t2x), fmaxf(t1y,t2y)), fmaxf(t1z,t2z)), 1e9f);

// ---------------------------------------------------------------------------
// Fused pre-pass, two block ranges:
//   [0, nGeomB)             : per-ray geometry checkpoints
//   [nGeomB, nGeomB+nConvB) : fp32 -> fp16 convert (2 thr/voxel) AND the
//                             occupancy bitmask via __ballot — odd (q=1)
//                             lanes already hold f27, so the mask pass and
//                             its 227 MB re-read are eliminated. A wave's
//                             32 odd lanes cover 32 consecutive voxels ->
//                             compress odd ballot bits to one u32, lane 1
//                             writes it. Mask = 262 KB, L2-resident (the
//                             r8 lesson: a 4 MB sigma array is NOT).
//
// CHANNEL-MAJOR voxel record (32 halfs = 64 B), s[] = half index:
//   s[ 0.. 8] = f0..f8  (ch0), s[9]  = pad
//   s[10..18] = f9..f17 (ch1), s[19] = pad
//   s[20..28] = f18..f26(ch2), s[29] = pad
//   s[30]     = sigma (f27),   s[31] = pad
// ---------------------------------------------------------------------------
__global__ __launch_bounds__(256) void prep_kernel(
    const float* __restrict__ tree, __half* __restrict__ vox, int nvox,
    const float* __restrict__ origins, const float* __restrict__ dirs_in,
    float* __restrict__ ckpt, unsigned int* __restrict__ occ_w,
    int nB, int nGeomB)
{
    int bid = (int)blockIdx.x;
    if (bid < nGeomB) {
        // ---- geometry checkpoints (one thread per ray, no gathers) ----
        int i = bid * 256 + threadIdx.x;
        if (i >= nB) return;
        RAY_SETUP(i);
        float ck[NSEG];
        float t = t0;
        ck[0] = t0;
#pragma unroll
        for (int k = 1; k < NSEG; ++k) {
            if (t < tmax) {
                for (int j = 0; j < SEG_STEPS; ++j) {
                    int fl;
                    t += march_step(t, ox, oy, oz, dx, dy, dz, idx, idy, idz, &fl);
                    if (t >= tmax) break;
                }
            }
            ck[k] = t;
        }
        float* cp = ckpt + (size_t)i * NSEG;
        *(float4*)(cp + 0) = make_float4(ck[0], ck[1], ck[2], ck[3]);
        *(float4*)(cp + 4) = make_float4(ck[4], ck[5], ck[6], ck[7]);
    } else {
        // ---- fp32 -> fp16 convert + channel-major reorder, 2 thr/voxel ----
        // nvox*2 is an exact multiple of 256, so every wave is full and
        // every lane reaches the ballot (no early returns on this path).
        int tid2 = (bid - nGeomB) * 256 + threadIdx.x;
        int v = tid2 >> 1;
        int q = tid2 & 1;
        bool occp = false;                       // odd lanes: sigma_f32 > 0
        if (v < nvox) {
            const float* src = tree + (size_t)v * DATA_DIM;
            uint4* d = (uint4*)(vox + (size_t)v * PAD_DIM) + q * 2;
            union Q { __half2 h[4]; uint4 u; } w;
            if (q == 0) {
                float4 L0 = *(const float4*)(src + 0);   // f0..f3
                float4 L1 = *(const float4*)(src + 4);   // f4..f7
                float4 L2 = *(const float4*)(src + 8);   // f8..f11
                float4 L3 = *(const float4*)(src + 12);  // f12..f15
                w.h[0] = __floats2half2_rn(L0.x, L0.y);  // f0 f1
                w.h[1] = __floats2half2_rn(L0.z, L0.w);  // f2 f3
                w.h[2] = __floats2half2_rn(L1.x, L1.y);  // f4 f5
                w.h[3] = __floats2half2_rn(L1.z, L1.w);  // f6 f7
                d[0] = w.u;
                w.h[0] = __floats2half2_rn(L2.x, 0.f);   // f8 pad
                w.h[1] = __floats2half2_rn(L2.y, L2.z);  // f9 f10
                w.h[2] = __floats2half2_rn(L2.w, L3.x);  // f11 f12
                w.h[3] = __floats2half2_rn(L3.y, L3.z);  // f13 f14
                d[1] = w.u;
            } else {
                float4 M0 = *(const float4*)(src + 12);  // f12..f15
                float4 M1 = *(const float4*)(src + 16);  // f16..f19
                float4 M2 = *(const float4*)(src + 20);  // f20..f23
                float4 M3 = *(const float4*)(src + 24);  // f24..f27
                w.h[0] = __floats2half2_rn(M0.w, M1.x);  // f15 f16
                w.h[1] = __floats2half2_rn(M1.y, 0.f);   // f17 pad
                w.h[2] = __floats2half2_rn(M1.z, M1.w);  // f18 f19
                w.h[3] = __floats2half2_rn(M2.x, M2.y);  // f20 f21
                d[0] = w.u;
                w.h[0] = __floats2half2_rn(M2.z, M2.w);  // f22 f23
                w.h[1] = __floats2half2_rn(M3.x, M3.y);  // f24 f25
                w.h[2] = __floats2half2_rn(M3.z, 0.f);   // f26 pad
                w.h[3] = __floats2half2_rn(M3.w, 0.f);   // sigma pad
                d[1] = w.u;
                occp = (M3.w > 0.0f);            // same f32 predicate as r5
            }
        }
        // whole wave converged here; odd ballot bit 2k+1 = voxel vb+k
        unsigned long long bal = __ballot(occp);
        if ((threadIdx.x & 63) == 1) {
            unsigned long long x = (bal >> 1) & 0x5555555555555555ull;
            x = (x | (x >> 1))  & 0x3333333333333333ull;
            x = (x | (x >> 2))  & 0x0f0f0f0f0f0f0f0full;
            x = (x | (x >> 4))  & 0x00ff00ff00ff00ffull;
            x = (x | (x >> 8))  & 0x0000ffff0000ffffull;
            x = (x | (x >> 16)) & 0x00000000ffffffffull;
            occ_w[v >> 5] = (unsigned int)x;     // v = wave's base voxel
        }
    }
}

// ---------------------------------------------------------------------------
// Main march: r5's verified structure + ONE-STEP-AHEAD MASK PROBE in plain C
// (the r8 rotation structure — compiler-preserved — but probing the 262 KB
// L2-resident bitmask instead of the 4 MB sigma array that caused 7M HBM
// line misses). Per iteration: compute step j+1's geometry and issue its
// mask-byte load (pure-geometry address, no dep on step j), then process
// step j with its mask byte already in hand. The record fetch stays inside
// the occupied branch exactly as in r5 (bit-identical gate, shade, and
// accumulation order). r7 lesson: no inline-asm loads / counted vmcnt.
// ---------------------------------------------------------------------------
typedef union { uint4 u[4]; h2f h[16]; _Float16 s[32]; } Rec;

__global__ __launch_bounds__(256, 8) void march_kernel(
    const __half* __restrict__ vox_grid,
    const unsigned char* __restrict__ occ_mask,
    const float* __restrict__ origins,
    const float* __restrict__ dirs_in,
    const float* __restrict__ viewdirs,
    const float* __restrict__ invradius,
    const float* __restrict__ ckpt,
    float* __restrict__ out, int nB)
{
    int tid = blockIdx.x * blockDim.x + threadIdx.x;
    int ray = tid >> 3;
    int seg = tid & 7;
    if (ray >= nB) return;

    RAY_SETUP(ray);

    float vx = viewdirs[3*ray+0], vy = viewdirs[3*ray+1], vz = viewdirs[3*ray+2];
    float irx = invradius[0], iry = invradius[1], irz = invradius[2];
    float qx = dx / irx, qy = dy / iry, qz = dz / irz;
    float delta_scale = sqrtf(qx*qx + qy*qy + qz*qz);

    const float C1 = 0.4886025119029199f;
    const float L2E = 1.4426950408889634f;   // log2(e), folded into SH + att
    float sh0 = 0.28209479177387814f;
    float sh1 = -C1 * vy;
    float sh2 =  C1 * vz;
    float sh3 = -C1 * vx;
    float sh4 =  1.0925484305920792f  * vx * vy;
    float sh5 = -1.0925484305920792f * vy * vz;
    float sh6 =  0.31539156525252005f * (2.0f*vz*vz - vx*vx - vy*vy);
    float sh7 = -1.0925484305920792f * vx * vz;
    float sh8 =  0.5462742152960396f  * (vx*vx - vy*vy);

    // loop-invariant fp16 coefficient pairs (pre-scaled by log2 e)
    h2f S01 = { (_Float16)(sh0*L2E), (_Float16)(sh1*L2E) };
    h2f S23 = { (_Float16)(sh2*L2E), (_Float16)(sh3*L2E) };
    h2f S45 = { (_Float16)(sh4*L2E), (_Float16)(sh5*L2E) };
    h2f S67 = { (_Float16)(sh6*L2E), (_Float16)(sh7*L2E) };
    h2f S8z = { (_Float16)(sh8*L2E), (_Float16)0.0f      };
    float nds = -delta_scale * L2E;          // att = 2^(dt*sigma*nds)

    float t = ckpt[(size_t)ray * NSEG + seg];
    float light = 1.0f;                      // segment-local transmittance
    float o0 = 0.f, o1 = 0.f, o2 = 0.f;

    // prologue: geometry + mask byte for step 0 (safe for any finite t)
    int fA;
    float dtA = march_step(t, ox, oy, oz, dx, dy, dz, idx, idy, idz, &fA);
    unsigned int mbA = occ_mask[fA >> 3];

    for (int j = 0; j < SEG_STEPS; ++j) {
        if (t >= tmax) break;

        // ---- step j+1 geometry + mask probe (independent of step j) ----
        float tn = t + dtA;
        int fB;
        float dtB = march_step(tn, ox, oy, oz, dx, dy, dz, idx, idy, idz, &fB);
        unsigned int mbB = occ_mask[fB >> 3];

        // ---- step j: gate on the already-resident mask byte ----
        if (mbA & (1u << (fA & 7))) {
            const uint4* vp = (const uint4*)(vox_grid + (size_t)fA * PAD_DIM);
            Rec rec;
            rec.u[0] = vp[0]; rec.u[1] = vp[1];
            rec.u[2] = vp[2]; rec.u[3] = vp[3];

            float sigma = (float)rec.s[30];          // >0 by mask (fp16 may
            float att = fexp2(dtA * sigma * nds);    //  round to 0 -> w=0)
            float la  = light * att;                 // light AFTER this step
            float w   = light - la;                  // = light*(1-att)
            light = la;

            // r_c pre-scaled by log2(e): sigmoid = rcp(1 + 2^-r)
            float r0 = fdot2(rec.h[ 4], S8z, fdot2(rec.h[ 3], S67,
                       fdot2(rec.h[ 2], S45, fdot2(rec.h[ 1], S23,
                       fdot2(rec.h[ 0], S01, 0.0f)))));
            float r1 = fdot2(rec.h[ 9], S8z, fdot2(rec.h[ 8], S67,
                       fdot2(rec.h[ 7], S45, fdot2(rec.h[ 6], S23,
                       fdot2(rec.h[ 5], S01, 0.0f)))));
            float r2 = fdot2(rec.h[14], S8z, fdot2(rec.h[13], S67,
                       fdot2(rec.h[12], S45, fdot2(rec.h[11], S23,
                       fdot2(rec.h[10], S01, 0.0f)))));

            float g0 = frcp(1.0f + fexp2neg(r0));
            float g1 = frcp(1.0f + fexp2neg(r1));
            float g2 = frcp(1.0f + fexp2neg(r2));

            o0 = fmaf(w, g0, o0);
            o1 = fmaf(w, g1, o1);
            o2 = fmaf(w, g2, o2);
        }

        // rotate
        t = tn; fA = fB; dtA = dtB; mbA = mbB;
    }

    // ---- 8-lane combine (lanes 8m..8m+7 hold segments 0..7 of one ray) ----
    float l0 = __shfl(light, 0, 8);
    float l1 = __shfl(light, 1, 8);
    float l2 = __shfl(light, 2, 8);
    float l3 = __shfl(light, 3, 8);
    float l4 = __shfl(light, 4, 8);
    float l5 = __shfl(light, 5, 8);
    float l6 = __shfl(light, 6, 8);
    float l7 = __shfl(light, 7, 8);

    float P = 1.0f;
    if (seg > 0) P *= l0;
    if (seg > 1) P *= l1;
    if (seg > 2) P *= l2;
    if (seg > 3) P *= l3;
    if (seg > 4) P *= l4;
    if (seg > 5) P *= l5;
    if (seg > 6) P *= l6;
    float total_light = l0*l1*l2*l3*l4*l5*l6*l7;

    o0 *= P; o1 *= P; o2 *= P;
    o0 += __shfl_xor(o0, 1, 8); o0 += __shfl_xor(o0, 2, 8); o0 += __shfl_xor(o0, 4, 8);
    o1 += __shfl_xor(o1, 1, 8); o1 += __shfl_xor(o1, 2, 8); o1 += __shfl_xor(o1, 4, 8);
    o2 += __shfl_xor(o2, 1, 8); o2 += __shfl_xor(o2, 2, 8); o2 += __shfl_xor(o2, 4, 8);

    if (seg == 0) {
        out[3*ray+0] = o0 + total_light * BG;
        out[3*ray+1] = o1 + total_light * BG;
        out[3*ray+2] = o2 + total_light * BG;
    }
}

extern "C" void kernel_launch(void* const* d_in, const int* in_sizes, int n_in,
                              void* d_out, int out_size, void* d_ws, size_t ws_size,
                              hipStream_t stream) {
    const float* tree      = (const float*)d_in[0];
    const float* origins   = (const float*)d_in[1];
    const float* dirs      = (const float*)d_in[2];
    const float* viewdirs  = (const float*)d_in[3];
    const float* invradius = (const float*)d_in[4];
    float* out = (float*)d_out;

    int nB   = in_sizes[1] / 3;
    int nvox = in_sizes[0] / DATA_DIM;

    const int block = 256;
    __half* hgrid = (__half*)d_ws;
    float* ckpt = (float*)((char*)d_ws + (size_t)nvox * PAD_DIM * sizeof(__half));
    unsigned int* occ_w =
        (unsigned int*)((char*)ckpt + (size_t)nB * NSEG * sizeof(float));

    int nGeomB = (nB + block - 1) / block;
    int nConvB = (nvox * 2 + block - 1) / block;
    prep_kernel<<<nGeomB + nConvB, block, 0, stream>>>(
        tree, hgrid, nvox, origins, dirs, ckpt, occ_w, nB, nGeomB);

    int nmarch = nB * NSEG;
    march_kernel<<<(nmarch + block - 1) / block, block, 0, stream>>>(
        hgrid, (const unsigned char*)occ_w, origins, dirs, viewdirs, invradius,
        ckpt, out, nB);
    (void)ws_size;
}